// Round 2
// baseline (539.526 us; speedup 1.0000x reference)
//
#include <hip/hip_runtime.h>

typedef unsigned short u16;
typedef unsigned int   u32;

#define R_DIM 400
#define F_DIM 256
#define M_TOT 51200
#define SKIP  0x80000000u

__device__ __forceinline__ float bf2f(u16 u) {
    union { u32 i; float f; } x; x.i = ((u32)u) << 16; return x.f;
}
__device__ __forceinline__ u16 f2bf(float f) {
    union { float f; u32 i; } x; x.f = f;
    u32 r = x.i + 0x7FFFu + ((x.i >> 16) & 1u);   // RNE
    return (u16)(r >> 16);
}
// mode: 0 = bf16 tensors, 1 = fp32 tensors
__device__ __forceinline__ float loadF(const void* p, long long idx, int mode) {
    return mode ? ((const float*)p)[idx] : bf2f(((const u16*)p)[idx]);
}

// ---------------------------------------------------------------------------
// Kernel 0: dtype sniffer. Even-indexed u16s of A: bf16 array -> bf16 values
// in [0,1) (top nibble 0x3 with prob ~1); fp32 array -> low mantissa halves
// (top nibble uniform, prob 1/16). Writes mode flag to ws[0].
// ---------------------------------------------------------------------------
__global__ void sniff_kernel(const void* __restrict__ A, u32* __restrict__ flag) {
    const int lane = threadIdx.x;          // 64 threads, 1 block
    u16 v = ((const u16*)A)[lane * 2];     // even halfwords
    int isbf = ((v >> 12) == 0x3) ? 1 : 0;
    unsigned long long m = __ballot(isbf);
    if (lane == 0) flag[0] = (__popcll(m) >= 32) ? 0u : 1u;
}

// ---------------------------------------------------------------------------
// Kernel 1: per-row stable-descending-argsort ranks of columns {0, 8..12}.
// rank(c) = #{j: A[j]>A[c]} + #{j<c: A[j]==A[c]}.
// Emits 8 u32 slots per row: 6 rank positions, diag position (SKIP if dup),
// SKIP pad. Weights are NOT packed — gather reloads from A (lossless in
// both modes). One wave per row.
// ---------------------------------------------------------------------------
__global__ __launch_bounds__(256) void ranks_kernel(const void* __restrict__ A,
                                                    const u32* __restrict__ flag,
                                                    u32* __restrict__ sparse) {
    const int mode = (int)flag[0];
    const int cols[6] = {0, 8, 9, 10, 11, 12};
    const int wid = threadIdx.x >> 6, lane = threadIdx.x & 63;
    const int row = blockIdx.x * 4 + wid;
    const long long base = (long long)row * R_DIM;

    float ref[6];
#pragma unroll
    for (int k = 0; k < 6; k++) ref[k] = loadF(A, base + cols[k], mode);

    int cnt[6] = {0, 0, 0, 0, 0, 0};
    for (int j = lane; j < R_DIM; j += 64) {
        float a = loadF(A, base + j, mode);
#pragma unroll
        for (int k = 0; k < 6; k++)
            cnt[k] += (a > ref[k] || (a == ref[k] && j < cols[k])) ? 1 : 0;
    }
    u32 p0 = (u32)cnt[0] | ((u32)cnt[1] << 10) | ((u32)cnt[2] << 20);
    u32 p1 = (u32)cnt[3] | ((u32)cnt[4] << 10) | ((u32)cnt[5] << 20);
#pragma unroll
    for (int off = 32; off; off >>= 1) {
        p0 += __shfl_xor(p0, off);
        p1 += __shfl_xor(p1, off);
    }

    if (lane < 8) {
        u32 slot;
        if (lane < 6) {
            unsigned long long all = (((unsigned long long)p1) << 30) | (unsigned long long)p0;
            slot = (u32)((all >> (10 * lane)) & 1023u);
        } else if (lane == 6) {
            int i  = row % R_DIM;   // diagonal column
            int r0 = p0 & 1023, r1 = (p0 >> 10) & 1023, r2 = (p0 >> 20) & 1023;
            int r3 = p1 & 1023, r4 = (p1 >> 10) & 1023, r5 = (p1 >> 20) & 1023;
            bool dup = (i == r0) | (i == r1) | (i == r2) | (i == r3) | (i == r4) | (i == r5);
            slot = dup ? SKIP : (u32)i;
        } else {
            slot = SKIP;
        }
        sparse[(long long)row * 8 + lane] = slot;
    }
}

// ---------------------------------------------------------------------------
// Kernel 2: fused gather + NAIVE fp32 GEMM (no MFMA, no fragment layouts —
// deliberately layout-risk-free for this diagnostic round).
// Block = 256 threads = 4 waves, 32 rows per block.
// Phase 1: wave w gathers rows {w, w+4, ...}: agg[r][f] fp32 -> LDS.
// Phase 2: thread t computes column n=t for all 32 rows (LDS broadcast reads).
// ---------------------------------------------------------------------------
__global__ __launch_bounds__(256) void gcn_naive(const void* __restrict__ A,
                                                 const void* __restrict__ feats,
                                                 const void* __restrict__ W,
                                                 const void* __restrict__ bias,
                                                 const u32* __restrict__ flag,
                                                 const u32* __restrict__ sparse,
                                                 void* __restrict__ out) {
    __shared__ __align__(16) float agg[32][260];   // 260 = 4*65 -> float4-aligned rows
    const int mode = (int)flag[0];
    const int tid = threadIdx.x, wid = tid >> 6, lane = tid & 63;
    const int m0 = blockIdx.x * 32;

    // ---- phase 1: sparse gather (fp32 accumulate) ----
    for (int r = wid; r < 32; r += 4) {
        const int row = m0 + r;
        const int bh  = row / R_DIM;
        const long long abase = (long long)row * R_DIM;
        const long long fbase = (long long)bh * R_DIM * F_DIM + lane * 4;
        float a0 = 0.f, a1 = 0.f, a2 = 0.f, a3 = 0.f;
#pragma unroll
        for (int s = 0; s < 8; s++) {
            u32 e = sparse[(long long)row * 8 + s];
            if (e == SKIP) continue;              // wave-uniform branch
            float w = loadF(A, abase + (int)e, mode);
            long long fo = fbase + (long long)e * F_DIM;
            a0 += w * loadF(feats, fo + 0, mode);
            a1 += w * loadF(feats, fo + 1, mode);
            a2 += w * loadF(feats, fo + 2, mode);
            a3 += w * loadF(feats, fo + 3, mode);
        }
        agg[r][lane * 4 + 0] = a0;
        agg[r][lane * 4 + 1] = a1;
        agg[r][lane * 4 + 2] = a2;
        agg[r][lane * 4 + 3] = a3;
    }
    __syncthreads();

    // ---- phase 2: naive GEMM, thread t -> output column n = t ----
    const int n = tid;
    const long long wb = (long long)n * F_DIM;
    float acc[32];
#pragma unroll
    for (int r = 0; r < 32; r++) acc[r] = 0.f;

    for (int k = 0; k < 256; k += 4) {
        float w0 = loadF(W, wb + k + 0, mode);
        float w1 = loadF(W, wb + k + 1, mode);
        float w2 = loadF(W, wb + k + 2, mode);
        float w3 = loadF(W, wb + k + 3, mode);
#pragma unroll
        for (int r = 0; r < 32; r++) {
            const float4 av = *(const float4*)&agg[r][k];
            acc[r] += av.x * w0 + av.y * w1 + av.z * w2 + av.w * w3;
        }
    }

    const float bn = loadF(bias, n, mode);
#pragma unroll
    for (int r = 0; r < 32; r++) {
        const long long off = (long long)(m0 + r) * F_DIM + n;
        float v = fmaxf(acc[r] + bn, 0.f) + loadF(feats, off, mode);
        if (mode) ((float*)out)[off] = v;
        else      ((u16*)out)[off]   = f2bf(v);
    }
}

extern "C" void kernel_launch(void* const* d_in, const int* in_sizes, int n_in,
                              void* d_out, int out_size, void* d_ws, size_t ws_size,
                              hipStream_t stream) {
    const void* A     = d_in[0];   // [16,8,400,400]
    const void* feats = d_in[1];   // [16,8,400,256]
    const void* W     = d_in[2];   // [256,256]
    const void* bias  = d_in[3];   // [256]
    u32* flag   = (u32*)d_ws;                    // ws[0]: mode flag
    u32* sparse = (u32*)d_ws + 16;               // 51200*8 u32 = 1.6 MB

    sniff_kernel<<<1, 64, 0, stream>>>(A, flag);
    ranks_kernel<<<M_TOT / 4, 256, 0, stream>>>(A, flag, sparse);
    gcn_naive<<<M_TOT / 32, 256, 0, stream>>>(A, feats, W, bias, flag, sparse, d_out);
}

// Round 6
// 308.911 us; speedup vs baseline: 1.7465x; 1.7465x over previous
//
#include <hip/hip_runtime.h>

typedef unsigned short u16;
typedef unsigned int   u32;
typedef __bf16 bf16x8 __attribute__((ext_vector_type(8)));
typedef float  f32x4  __attribute__((ext_vector_type(4)));
typedef u32    u32x4  __attribute__((ext_vector_type(4)));
typedef u16    u16x4  __attribute__((ext_vector_type(4)));
typedef u16    u16x8v __attribute__((ext_vector_type(8)));

#define R_DIM 400
#define F_DIM 256
#define M_TOT 51200
#define SKIP  0x80000000u

__device__ __forceinline__ u16 f2bf(float f) {
    union { float f; u32 i; } x; x.f = f;
    u32 r = x.i + 0x7FFFu + ((x.i >> 16) & 1u);   // RNE
    return (u16)(r >> 16);
}

// ---------------------------------------------------------------------------
// Kernel 1: per-row stable-descending-argsort ranks of cols {0,8..12} (fp32).
// rank(c) = #{j: A[j]>A[c]} + #{j<c: A[j]==A[c]}  — formula verified by the
// passing round-2 run (identical compare semantics, fp32 path).
// Slot = position or SKIP (dup-diag / pad). 16 rows/block, float4 loads.
// ---------------------------------------------------------------------------
__global__ __launch_bounds__(256) void ranks_f32(const float* __restrict__ A,
                                                 u32* __restrict__ sparse) {
    const int cols[6] = {0, 8, 9, 10, 11, 12};
    const int wid = threadIdx.x >> 6, lane = threadIdx.x & 63;
#pragma unroll
    for (int rr = 0; rr < 4; rr++) {
        const int row = blockIdx.x * 16 + wid * 4 + rr;
        const float* Ar = A + (size_t)row * R_DIM;

        float ref[6];
        ref[0] = Ar[0];
#pragma unroll
        for (int k = 1; k < 6; k++) ref[k] = Ar[7 + k];

        int cnt[6] = {0, 0, 0, 0, 0, 0};
#pragma unroll
        for (int base = 0; base < 400; base += 256) {
            int j0 = base + lane * 4;
            if (j0 < R_DIM) {
                float4 v = *(const float4*)(Ar + j0);
                float vv[4] = {v.x, v.y, v.z, v.w};
#pragma unroll
                for (int jj = 0; jj < 4; jj++) {
                    float a = vv[jj]; int j = j0 + jj;
#pragma unroll
                    for (int k = 0; k < 6; k++)
                        cnt[k] += (a > ref[k] || (a == ref[k] && j < cols[k])) ? 1 : 0;
                }
            }
        }
        u32 p0 = (u32)cnt[0] | ((u32)cnt[1] << 10) | ((u32)cnt[2] << 20);
        u32 p1 = (u32)cnt[3] | ((u32)cnt[4] << 10) | ((u32)cnt[5] << 20);
#pragma unroll
        for (int off = 32; off; off >>= 1) {
            p0 += __shfl_xor(p0, off);
            p1 += __shfl_xor(p1, off);
        }

        if (lane < 8) {
            u32 slot;
            if (lane < 6) {
                unsigned long long all = (((unsigned long long)p1) << 30) | (unsigned long long)p0;
                slot = (u32)((all >> (10 * lane)) & 1023u);
            } else if (lane == 6) {
                int i  = row % R_DIM;
                int r0 = p0 & 1023, r1 = (p0 >> 10) & 1023, r2 = (p0 >> 20) & 1023;
                int r3 = p1 & 1023, r4 = (p1 >> 10) & 1023, r5 = (p1 >> 20) & 1023;
                bool dup = (i == r0) | (i == r1) | (i == r2) | (i == r3) | (i == r4) | (i == r5);
                slot = dup ? SKIP : (u32)i;
            } else {
                slot = SKIP;
            }
            sparse[(size_t)row * 8 + lane] = slot;
        }
    }
}

// ---------------------------------------------------------------------------
// Kernel 2: convert fp32 W -> bf16 B-fragments.
// Fragment g = (ks 0..7, T 0..15, L 0..63):
//   Wf[g][0..7] = bf16( W[T*16 + (L&15)][ks*32 + (L>>4)*8 .. +7] )
// ---------------------------------------------------------------------------
__global__ __launch_bounds__(256) void wprep_f32(const float* __restrict__ W,
                                                 u16* __restrict__ Wf) {
    int g  = blockIdx.x * 256 + threadIdx.x;   // 0..8191
    int ks = g >> 10;
    int T  = (g >> 6) & 15;
    int L  = g & 63;
    int n  = T * 16 + (L & 15);
    int k  = ks * 32 + (L >> 4) * 8;
    const float* wp = W + (size_t)n * F_DIM + k;
    float4 lo = *(const float4*)wp;
    float4 hi = *(const float4*)(wp + 4);
    u16x8v t;
    t[0] = f2bf(lo.x); t[1] = f2bf(lo.y); t[2] = f2bf(lo.z); t[3] = f2bf(lo.w);
    t[4] = f2bf(hi.x); t[5] = f2bf(hi.y); t[6] = f2bf(hi.z); t[7] = f2bf(hi.w);
    *(u16x8v*)(Wf + (size_t)g * 8) = t;
}

// ---------------------------------------------------------------------------
// Kernel 3: fused gather + MFMA GEMM + epilogue (fp32 in/out).
// 64 rows/block, 800 blocks, XCD-contiguous block swizzle.
// Probe-calibrated C/D decode (integer probe, dtype-independent, invariant
// to operand-role and shared-k-permutation conventions).
// ---------------------------------------------------------------------------
__global__ __launch_bounds__(256) void gcn_mfma(const float* __restrict__ A,
                                                const float* __restrict__ feats,
                                                const u16*  __restrict__ Wf,
                                                const float* __restrict__ bias,
                                                const u32*  __restrict__ sparse,
                                                float* __restrict__ out) {
    __shared__ __align__(16) u16 agg_lds[64][264];   // bf16 agg tile
    __shared__ __align__(16) u16 probeA[16][32];
    __shared__ __align__(16) u16 probeB[16][32];

    const int tid = threadIdx.x, wid = tid >> 6, lane = tid & 63;
    // XCD swizzle: blocks x+8y -> x*100+y so each XCD sees a contiguous span
    const int bid = (int)blockIdx.x;
    const int m0  = ((bid & 7) * 100 + (bid >> 3)) * 64;
    const int kg  = (lane >> 4) << 3;

    // probe tiles: A[m][0]=m, A[m][1]=1; B[n][0]=16, B[n][1]=n  -> D=16m+n
    for (int e = tid; e < 512; e += 256) {
        int r = e >> 5, k = e & 31;
        probeA[r][k] = (k == 0) ? f2bf((float)r) : ((k == 1) ? f2bf(1.0f) : (u16)0);
        probeB[r][k] = (k == 0) ? f2bf(16.0f)    : ((k == 1) ? f2bf((float)r) : (u16)0);
    }

    // ---- phase 1: sparse gather (fp32 math, float4 loads) -> bf16 LDS ----
    for (int r = wid; r < 64; r += 4) {
        const int row = m0 + r;
        const int bh  = row / R_DIM;
        const float* fb = feats + (size_t)bh * R_DIM * F_DIM + lane * 4;
        const float* Ar = A + (size_t)row * R_DIM;
        const u32* sp = sparse + (size_t)row * 8;
        float a0 = 0.f, a1 = 0.f, a2 = 0.f, a3 = 0.f;
#pragma unroll
        for (int s = 0; s < 8; s++) {
            u32 e = sp[s];
            if (e == SKIP) continue;          // wave-uniform
            float w = Ar[(int)e];
            float4 f4 = *(const float4*)(fb + (size_t)e * F_DIM);
            a0 += w * f4.x; a1 += w * f4.y; a2 += w * f4.z; a3 += w * f4.w;
        }
        u16x4 st = { f2bf(a0), f2bf(a1), f2bf(a2), f2bf(a3) };
        *(u16x4*)&agg_lds[r][lane * 4] = st;
    }
    __syncthreads();

    // ---- probe MFMA: decode true per-register (row,col) ----
    int rowi[4], coli[4];
    {
        bf16x8 pa = *(const bf16x8*)&probeA[lane & 15][kg];
        bf16x8 pb = *(const bf16x8*)&probeB[lane & 15][kg];
        f32x4 pd = {0.f, 0.f, 0.f, 0.f};
        pd = __builtin_amdgcn_mfma_f32_16x16x32_bf16(pa, pb, pd, 0, 0, 0);
#pragma unroll
        for (int reg = 0; reg < 4; reg++) {
            int v = (int)(pd[reg] + 0.5f);
            rowi[reg] = v >> 4;
            coli[reg] = v & 15;
        }
    }

    // ---- phase 2: MFMA K-loop (no barriers; Wf frags direct from global) ----
    f32x4 acc[4][4];
#pragma unroll
    for (int mt = 0; mt < 4; mt++)
#pragma unroll
        for (int nt = 0; nt < 4; nt++)
            acc[mt][nt] = (f32x4){0.f, 0.f, 0.f, 0.f};

    for (int ks = 0; ks < 8; ks++) {
        bf16x8 af[4], bfr[4];
#pragma unroll
        for (int mt = 0; mt < 4; mt++)
            af[mt] = *(const bf16x8*)&agg_lds[mt * 16 + (lane & 15)][ks * 32 + kg];
#pragma unroll
        for (int nt = 0; nt < 4; nt++) {
            int T = wid * 4 + nt;             // n-tile index: wave w owns T=4w..4w+3
            u32x4 v = *(const u32x4*)(Wf + ((size_t)(ks * 16 + T) * 64 + lane) * 8);
            bfr[nt] = __builtin_bit_cast(bf16x8, v);
        }
#pragma unroll
        for (int mt = 0; mt < 4; mt++)
#pragma unroll
            for (int nt = 0; nt < 4; nt++)
                acc[mt][nt] = __builtin_amdgcn_mfma_f32_16x16x32_bf16(
                    af[mt], bfr[nt], acc[mt][nt], 0, 0, 0);
    }

    // ---- epilogue: relu(acc + b) + feats -> out (fp32) ----
#pragma unroll
    for (int nt = 0; nt < 4; nt++) {
        int nb = wid * 64 + nt * 16;
#pragma unroll
        for (int reg = 0; reg < 4; reg++) {
            int gn = nb + coli[reg];
            float bn = bias[gn];
#pragma unroll
            for (int mt = 0; mt < 4; mt++) {
                int gm = m0 + mt * 16 + rowi[reg];
                size_t off = (size_t)gm * F_DIM + gn;
                out[off] = fmaxf(acc[mt][nt][reg] + bn, 0.f) + feats[off];
            }
        }
    }
}

extern "C" void kernel_launch(void* const* d_in, const int* in_sizes, int n_in,
                              void* d_out, int out_size, void* d_ws, size_t ws_size,
                              hipStream_t stream) {
    const float* A     = (const float*)d_in[0];   // [16,8,400,400] fp32
    const float* feats = (const float*)d_in[1];   // [16,8,400,256] fp32
    const float* W     = (const float*)d_in[2];   // [256,256] fp32
    const float* bias  = (const float*)d_in[3];   // [256] fp32
    float* out = (float*)d_out;                   // [16,8,400,256] fp32

    u32* sparse = (u32*)d_ws;                                  // 1.6384 MB
    u16* Wf     = (u16*)((char*)d_ws + (size_t)M_TOT * 8 * 4); // 128 KB

    ranks_f32<<<M_TOT / 16, 256, 0, stream>>>(A, sparse);
    wprep_f32<<<32, 256, 0, stream>>>(W, Wf);
    gcn_mfma<<<M_TOT / 64, 256, 0, stream>>>(A, feats, Wf, bias, sparse, out);
}